// Round 9
// baseline (786.169 us; speedup 1.0000x reference)
//
#include <hip/hip_runtime.h>
#include <cmath>

// ---------- constants ----------
#define IMG 131072        // 512*256 per batch image
#define BIGF 1048576      // 8*512*256

#define CF_RELU 1
#define CF_RES  2
#define CF_BN   4

typedef __attribute__((ext_vector_type(8))) short short8;
typedef __attribute__((ext_vector_type(4))) short short4v;
typedef __attribute__((ext_vector_type(4))) float f32x4;

__device__ __forceinline__ float wave_sum(float v){
    #pragma unroll
    for (int off = 32; off; off >>= 1) v += __shfl_xor(v, off);
    return v;
}

__device__ __forceinline__ unsigned short bf16_rn(float x){
    union { float f; unsigned u; } v; v.f = x;
    unsigned r = v.u + 0x7FFF + ((v.u >> 16) & 1);
    return (unsigned short)(r >> 16);
}
__device__ __forceinline__ float bf16_to_f(unsigned short h){
    union { float f; unsigned u; } v; v.u = ((unsigned)h) << 16;
    return v.f;
}

// ---------- job structs (paired launches across the two branches) ----------
struct GapJobs  { const float* x[2]; float* o[2]; };
struct G8Job    { const float* in; const float* W; const float* bias; const float* add; float* out; };
struct G8Jobs   { G8Job j[4]; };
struct AAJobs   { const float* qkv[2]; float* om[2]; };
struct LnJobs   { const float* in[2]; float* out[2]; };
struct UpJobs   { const float* in[2]; float* out[2]; };
struct SAJobs   { const float* q8[2]; const float* k8[2]; float* aw[2]; };
struct SPJobs   { const float* aw[2]; const float* v[2]; float* out[2]; };
struct ConvJob  { const float* X; const float* X2; const float* W; const float* B; const float* R;
                  const float* bng; const float* bnb; float* O; int flags; };
struct ConvJobs { ConvJob j[6]; };
struct PixJob   { const float* Q; const float* K; const float* V; float* O0; float* O1; };
struct PixJobs  { PixJob j[2]; };

// ---------- GAP: mean over 256 spatial ----------
__global__ __launch_bounds__(64) void k_gap(GapJobs jo){
    const int br = blockIdx.y;
    const int bc = blockIdx.x;           // b*512 + c
    const int lane = threadIdx.x;
    const float* p = jo.x[br] + (size_t)bc * 256;
    float s = p[lane] + p[lane + 64] + p[lane + 128] + p[lane + 192];
    s = wave_sum(s);
    if (lane == 0) jo.o[br][bc] = s * (1.0f / 256.0f);
}

// ---------- tiny GEMM: out[8,O] = in[8,512] @ W[O,512]^T + bias (+add) ----------
__global__ __launch_bounds__(64) void k_gemm8(G8Jobs jo, int add_off, int add_stride, int O, int relu){
    const G8Job j = jo.j[blockIdx.y];
    const int o = blockIdx.x;
    const int lane = threadIdx.x;
    const float* wr = j.W + (size_t)o * 512;
    float acc[8] = {0,0,0,0,0,0,0,0};
    #pragma unroll
    for (int i = 0; i < 8; i++){
        float w = wr[lane + 64*i];
        #pragma unroll
        for (int b = 0; b < 8; b++) acc[b] += w * j.in[b*512 + lane + 64*i];
    }
    #pragma unroll
    for (int b = 0; b < 8; b++) acc[b] = wave_sum(acc[b]);
    if (lane < 8){
        float v = acc[0];
        #pragma unroll
        for (int b = 1; b < 8; b++) if (lane == b) v = acc[b];
        v += j.bias[o];
        if (j.add) v += j.add[lane*add_stride + add_off + o];
        if (relu) v = fmaxf(v, 0.f);
        j.out[(size_t)lane * O + o] = v;
    }
}

// ---------- asri batch-axis attention; writes merged o [8,512] ----------
__global__ __launch_bounds__(64) void k_asri_attn(AAJobs jo){
    const int br = blockIdx.y;
    const float* qkv = jo.qkv[br];
    const int h = blockIdx.x >> 3, b = blockIdx.x & 7, c = threadIdx.x;
    const int ci = c*8 + h;
    float qc = qkv[b*2048 + ci];
    float s[8];
    #pragma unroll
    for (int d = 0; d < 8; d++){
        float p = qc * qkv[d*2048 + 512 + ci];
        p = wave_sum(p);
        s[d] = p * 0.125f;
    }
    float m = s[0];
    #pragma unroll
    for (int d = 1; d < 8; d++) m = fmaxf(m, s[d]);
    float sum = 0.f;
    #pragma unroll
    for (int d = 0; d < 8; d++){ s[d] = __expf(s[d]-m); sum += s[d]; }
    float r = 1.f / sum;
    float oc = 0.f;
    #pragma unroll
    for (int d = 0; d < 8; d++) oc += s[d]*r * qkv[d*2048 + 1024 + ci];
    jo.om[br][b*512 + ci] = oc;
}

// ---------- LN over 512, 8 rows ----------
__global__ __launch_bounds__(64) void k_ln8(LnJobs jo,
    const float* __restrict__ g, const float* __restrict__ be)
{
    const int br = blockIdx.y;
    const int b = blockIdx.x, lane = threadIdx.x;
    const float* in = jo.in[br];
    float v[8]; float s = 0.f;
    #pragma unroll
    for (int i = 0; i < 8; i++){ v[i] = in[b*512 + lane + 64*i]; s += v[i]; }
    s = wave_sum(s);
    float mean = s * (1.f/512.f);
    float q = 0.f;
    #pragma unroll
    for (int i = 0; i < 8; i++){ float d = v[i]-mean; q += d*d; }
    q = wave_sum(q);
    float rstd = rsqrtf(q*(1.f/512.f) + 1e-5f);
    #pragma unroll
    for (int i = 0; i < 8; i++){
        int c = lane + 64*i;
        jo.out[br][b*512 + c] = (v[i]-mean)*rstd*g[c] + be[c];
    }
}

// ---------- bilinear upsample 4x4 -> 16x16 align_corners ----------
__global__ __launch_bounds__(256) void k_up(UpJobs jo){
    const int br = blockIdx.y;
    const int idx = blockIdx.x*256 + threadIdx.x;
    const int x = idx & 15, y = (idx >> 4) & 15, bc = idx >> 8;
    float px = (float)(x*3) / 15.0f, py = (float)(y*3) / 15.0f;
    int lx = (int)px, ly = (int)py;
    float wx = px - lx, wy = py - ly;
    int hx = min(lx+1, 3), hy = min(ly+1, 3);
    const float* p = jo.in[br] + (size_t)bc * 16;
    float v00 = p[ly*4+lx], v01 = p[ly*4+hx], v10 = p[hy*4+lx], v11 = p[hy*4+hx];
    float a0 = v00*(1.f-wy) + v10*wy;
    float a1 = v01*(1.f-wy) + v11*wy;
    jo.out[br][idx] = a0*(1.f-wx) + a1*wx;
}

// ---------- conv1x1 via split-bf16 MFMA: 512 thr, K-split across 2 wave-groups ----------
// Optional X2: staging computes (X + X2) in fp32 before the hi/lo split (used to
// sum the two pixel-attention d-group partials for free inside the pp conv).
#define LDK 40
__device__ __forceinline__ void convm_body(
    const float* __restrict__ Xb, const float* __restrict__ X2b,
    const float* __restrict__ W,
    const float* __restrict__ bias, const float* __restrict__ resb,
    const float* __restrict__ bng, const float* __restrict__ bnb, float bninv,
    float* __restrict__ outb, int flags, int o0, int n0, unsigned short* lds)
{
    const int tid512 = threadIdx.x;
    const int g   = tid512 >> 8;          // K-group
    const int tid = tid512 & 255;
    unsigned short* sAh = lds + g*10240;
    unsigned short* sAl = sAh + 2560;
    unsigned short* sBh = sAl + 2560;
    unsigned short* sBl = sBh + 2560;
    const int wv = tid >> 6, lane = tid & 63;
    const int quad = lane >> 4, l16 = lane & 15;
    const int wo = (wv >> 1) * 32, wn = (wv & 1) * 32;
    const int so  = tid >> 2, sk8 = (tid & 3) * 8;
    const int sp  = tid & 15, sn  = (tid >> 4) * 4;

    const float* wrow  = W + (size_t)(o0 + so)*512 + g*256 + sk8;
    const float* xrow  = Xb + (size_t)(g*256 + 2*sp)*256 + n0 + sn;
    const float* x2row = X2b ? X2b + (size_t)(g*256 + 2*sp)*256 + n0 + sn : nullptr;

    f32x4 acc[2][2] = {};
    float4 a0 = *(const float4*)(wrow);
    float4 a1 = *(const float4*)(wrow + 4);
    float4 x0 = *(const float4*)(xrow);
    float4 x1 = *(const float4*)(xrow + 256);
    if (x2row){
        float4 y0 = *(const float4*)(x2row);
        float4 y1 = *(const float4*)(x2row + 256);
        x0.x+=y0.x; x0.y+=y0.y; x0.z+=y0.z; x0.w+=y0.w;
        x1.x+=y1.x; x1.y+=y1.y; x1.z+=y1.z; x1.w+=y1.w;
    }

    for (int k0 = 0; k0 < 256; k0 += 32){
        __syncthreads();
        {
            float wa[8] = {a0.x,a0.y,a0.z,a0.w,a1.x,a1.y,a1.z,a1.w};
            #pragma unroll
            for (int j = 0; j < 4; j++){
                unsigned short h0 = bf16_rn(wa[2*j]);
                unsigned short h1 = bf16_rn(wa[2*j+1]);
                unsigned short g0 = bf16_rn(wa[2*j]   - bf16_to_f(h0));
                unsigned short g1 = bf16_rn(wa[2*j+1] - bf16_to_f(h1));
                *(unsigned*)&sAh[so*LDK + sk8 + 2*j] = (unsigned)h0 | ((unsigned)h1 << 16);
                *(unsigned*)&sAl[so*LDK + sk8 + 2*j] = (unsigned)g0 | ((unsigned)g1 << 16);
            }
            float xe[4] = {x0.x,x0.y,x0.z,x0.w};
            float xo[4] = {x1.x,x1.y,x1.z,x1.w};
            #pragma unroll
            for (int j = 0; j < 4; j++){
                unsigned short h0 = bf16_rn(xe[j]);
                unsigned short h1 = bf16_rn(xo[j]);
                unsigned short g0 = bf16_rn(xe[j] - bf16_to_f(h0));
                unsigned short g1 = bf16_rn(xo[j] - bf16_to_f(h1));
                *(unsigned*)&sBh[(sn+j)*LDK + 2*sp] = (unsigned)h0 | ((unsigned)h1 << 16);
                *(unsigned*)&sBl[(sn+j)*LDK + 2*sp] = (unsigned)g0 | ((unsigned)g1 << 16);
            }
        }
        __syncthreads();
        if (k0 + 32 < 256){
            a0 = *(const float4*)(wrow + k0 + 32);
            a1 = *(const float4*)(wrow + k0 + 36);
            x0 = *(const float4*)(xrow + (size_t)(k0+32)*256);
            x1 = *(const float4*)(xrow + (size_t)(k0+32)*256 + 256);
            if (x2row){
                float4 y0 = *(const float4*)(x2row + (size_t)(k0+32)*256);
                float4 y1 = *(const float4*)(x2row + (size_t)(k0+32)*256 + 256);
                x0.x+=y0.x; x0.y+=y0.y; x0.z+=y0.z; x0.w+=y0.w;
                x1.x+=y1.x; x1.y+=y1.y; x1.z+=y1.z; x1.w+=y1.w;
            }
        }
        short8 ah[2], al[2], bh[2], bl[2];
        #pragma unroll
        for (int t = 0; t < 2; t++){
            int ai = (wo + 16*t + l16)*LDK + quad*8;
            ah[t] = *(const short8*)&sAh[ai];
            al[t] = *(const short8*)&sAl[ai];
            int bi = (wn + 16*t + l16)*LDK + quad*8;
            bh[t] = *(const short8*)&sBh[bi];
            bl[t] = *(const short8*)&sBl[bi];
        }
        #pragma unroll
        for (int mt = 0; mt < 2; mt++){
            #pragma unroll
            for (int nt = 0; nt < 2; nt++){
                acc[mt][nt] = __builtin_amdgcn_mfma_f32_16x16x32_bf16(ah[mt], bh[nt], acc[mt][nt], 0, 0, 0);
                acc[mt][nt] = __builtin_amdgcn_mfma_f32_16x16x32_bf16(ah[mt], bl[nt], acc[mt][nt], 0, 0, 0);
                acc[mt][nt] = __builtin_amdgcn_mfma_f32_16x16x32_bf16(al[mt], bh[nt], acc[mt][nt], 0, 0, 0);
            }
        }
    }
    // ---- cross-group reduction ----
    __syncthreads();
    float* red = (float*)lds;
    if (g == 1){
        float* r = red + tid*20;
        #pragma unroll
        for (int mt = 0; mt < 2; mt++)
            #pragma unroll
            for (int nt = 0; nt < 2; nt++)
                *(f32x4*)(r + (mt*2+nt)*4) = acc[mt][nt];
    }
    __syncthreads();
    if (g == 0){
        float* r = red + tid*20;
        #pragma unroll
        for (int mt = 0; mt < 2; mt++)
            #pragma unroll
            for (int nt = 0; nt < 2; nt++)
                acc[mt][nt] += *(const f32x4*)(r + (mt*2+nt)*4);
        #pragma unroll
        for (int mt = 0; mt < 2; mt++){
            #pragma unroll
            for (int nt = 0; nt < 2; nt++){
                const int n  = n0 + wn + 16*nt + l16;
                const int ob = o0 + wo + 16*mt + quad*4;
                #pragma unroll
                for (int rr = 0; rr < 4; rr++){
                    const int o = ob + rr;
                    float v = acc[mt][nt][rr] + bias[o];
                    if (flags & CF_BN)   v = v*(bninv*bng[o]) + bnb[o];
                    if (flags & CF_RELU) v = fmaxf(v, 0.f);
                    if (flags & CF_RES)  v += resb[(size_t)o*256 + n];
                    outb[(size_t)o*256 + n] = v;
                }
            }
        }
    }
}

__global__ __launch_bounds__(512) void k_convm(ConvJobs jo, float bninv)
{
    __shared__ unsigned short lds[20480];   // 40 KB
    const int z = blockIdx.z;
    const ConvJob j = jo.j[z >> 3];
    const int b = z & 7;
    convm_body(j.X + (size_t)b*IMG, j.X2 ? j.X2 + (size_t)b*IMG : nullptr,
               j.W, j.B, j.R ? j.R + (size_t)b*IMG : nullptr,
               j.bng, j.bnb, bninv, j.O + (size_t)b*IMG, j.flags,
               blockIdx.y*64, blockIdx.x*64, lds);
}

// ---------- sscm attention weights [h][b][d] ----------
__global__ __launch_bounds__(64) void k_sscm_attn(SAJobs jo)
{
    const int br = blockIdx.y;
    const int h = blockIdx.x >> 3, b = blockIdx.x & 7, c = threadIdx.x;
    const int ci = c*8 + h;
    float qc = jo.q8[br][b*512 + ci];
    float s[8];
    #pragma unroll
    for (int d = 0; d < 8; d++){
        float p = qc * jo.k8[br][d*512 + ci];
        p = wave_sum(p);
        s[d] = p * 0.125f;
    }
    float m = s[0];
    #pragma unroll
    for (int d = 1; d < 8; d++) m = fmaxf(m, s[d]);
    float sum = 0.f;
    #pragma unroll
    for (int d = 0; d < 8; d++){ s[d] = __expf(s[d]-m); sum += s[d]; }
    float r = 1.f/sum;
    if (c < 8){
        float v = s[0];
        #pragma unroll
        for (int d = 1; d < 8; d++) if (c == d) v = s[d];
        jo.aw[br][blockIdx.x*8 + c] = v*r;
    }
}

// ---------- sscm apply ----------
__global__ __launch_bounds__(256) void k_sscm_apply(SPJobs jo)
{
    const int br = blockIdx.y;
    const int idx = blockIdx.x*256 + threadIdx.x;
    const int pix = idx & 255, e = (idx >> 8) & 511, b = idx >> 17;
    const int h = e & 7;
    const float* aw = jo.aw[br] + (h*8 + b)*8;
    const float* v = jo.v[br];
    float acc = 0.f;
    #pragma unroll
    for (int d = 0; d < 8; d++) acc += aw[d] * v[(size_t)d*IMG + (size_t)e*256 + pix];
    jo.out[br][idx] = acc;
}

// ---------- pixel cross-batch attention v6: dg=2 groups x 4-d in-block loop ----------
// block = (nt, dg, b|br, h): 64 queries, loops d = dg*4 .. dg*4+3.  Softmax is
// per-d (independent), O accumulated in registers across the 4 d's and written
// ONCE with plain stores into the dg-group's partial buffer (no atomics, no zero).
// The pp conv sums the two partials via its X2 operand.
__global__ __launch_bounds__(256) void k_pixel_mfma(PixJobs jo)
{
    __shared__ char smem[61440];
    unsigned short* sQh = (unsigned short*)smem;      // [2 ks][64 q][40]
    unsigned short* sQl = sQh + 2*64*40;
    unsigned short* sKh = sQl + 2*64*40;              // [2 ks][128 m][40]
    unsigned short* sKl = sKh + 2*128*40;
    unsigned short* sP  = (unsigned short*)smem;      // [4 ks][64 q][40] (aliases Q)
    unsigned short* sVh = sP  + 4*64*40;              // [4 ks][64 c][40] (aliases K)
    unsigned short* sVl = sVh + 4*64*40;

    const int br = blockIdx.y >> 3, b = blockIdx.y & 7;
    const PixJob J = jo.j[br];
    const int nt = blockIdx.x & 3, dg = blockIdx.x >> 2;
    const int h = blockIdx.z;
    const int tid = threadIdx.x;
    const int wv = tid >> 6, lane = tid & 63;
    const int quad = lane >> 4, l16 = lane & 15;
    const int n0 = nt * 64;
    const size_t bQ = (size_t)b * IMG;

    {   // stage Q once (shared across all 4 d's)
        const int q = tid & 63, c0 = tid >> 6;
        #pragma unroll
        for (int r = 0; r < 16; r++){
            int c = c0 + 4*r;
            float v = J.Q[bQ + (size_t)(c*8+h)*256 + n0 + q];
            unsigned short hi = bf16_rn(v);
            unsigned short lo = bf16_rn(v - bf16_to_f(hi));
            int idx = (c>>5)*2560 + q*40 + (c&31);
            sQh[idx] = hi; sQl[idx] = lo;
        }
    }
    __syncthreads();
    short8 bqh[2], bql[2];   // Q fragments persist in regs for the whole kernel
    #pragma unroll
    for (int ks = 0; ks < 2; ks++){
        int idx = ks*2560 + (wv*16 + l16)*40 + quad*8;
        bqh[ks] = *(const short8*)&sQh[idx];
        bql[ks] = *(const short8*)&sQl[idx];
    }

    f32x4 oac[4] = {};
    #pragma unroll 1
    for (int dd = 0; dd < 4; dd++){
        const size_t bK = (size_t)(dg*4 + dd) * IMG;
        {   // stage K half 0 (overwrites previous iteration's V region; safe after trailing sync)
            const int mloc = tid & 127, cb0 = tid >> 7;
            #pragma unroll
            for (int p = 0; p < 4; p++){
                int cb = cb0 + 2*p;
                short8 hi8, lo8;
                #pragma unroll
                for (int j = 0; j < 8; j++){
                    float v = J.K[bK + (size_t)((cb*8+j)*8+h)*256 + mloc];
                    unsigned short hv = bf16_rn(v);
                    hi8[j] = (short)hv;
                    lo8[j] = (short)bf16_rn(v - bf16_to_f(hv));
                }
                int idx = (cb>>2)*5120 + mloc*40 + (cb&3)*8;
                *(short8*)&sKh[idx] = hi8;
                *(short8*)&sKl[idx] = lo8;
            }
        }
        __syncthreads();

        f32x4 S[16] = {};
        #pragma unroll
        for (int hm = 0; hm < 2; hm++){
            if (hm == 1){
                __syncthreads();
                const int mloc = tid & 127, cb0 = tid >> 7;
                #pragma unroll
                for (int p = 0; p < 4; p++){
                    int cb = cb0 + 2*p;
                    short8 hi8, lo8;
                    #pragma unroll
                    for (int j = 0; j < 8; j++){
                        float v = J.K[bK + (size_t)((cb*8+j)*8+h)*256 + 128 + mloc];
                        unsigned short hv = bf16_rn(v);
                        hi8[j] = (short)hv;
                        lo8[j] = (short)bf16_rn(v - bf16_to_f(hv));
                    }
                    int idx = (cb>>2)*5120 + mloc*40 + (cb&3)*8;
                    *(short8*)&sKh[idx] = hi8;
                    *(short8*)&sKl[idx] = lo8;
                }
                __syncthreads();
            }
            #pragma unroll
            for (int mtl = 0; mtl < 8; mtl++){
                #pragma unroll
                for (int ks = 0; ks < 2; ks++){
                    int idx = ks*5120 + (mtl*16 + l16)*40 + quad*8;
                    short8 ah = *(const short8*)&sKh[idx];
                    short8 al = *(const short8*)&sKl[idx];
                    S[hm*8+mtl] = __builtin_amdgcn_mfma_f32_16x16x32_bf16(ah, bqh[ks], S[hm*8+mtl], 0, 0, 0);
                    S[hm*8+mtl] = __builtin_amdgcn_mfma_f32_16x16x32_bf16(ah, bql[ks], S[hm*8+mtl], 0, 0, 0);
                    S[hm*8+mtl] = __builtin_amdgcn_mfma_f32_16x16x32_bf16(al, bqh[ks], S[hm*8+mtl], 0, 0, 0);
                }
            }
        }

        {   // softmax over all 256 m per q-column (NO scale -- matches source)
            float mx = -3.4e38f;
            #pragma unroll
            for (int t = 0; t < 16; t++)
                #pragma unroll
                for (int r = 0; r < 4; r++) mx = fmaxf(mx, S[t][r]);
            mx = fmaxf(mx, __shfl_xor(mx, 16));
            mx = fmaxf(mx, __shfl_xor(mx, 32));
            float sum = 0.f;
            #pragma unroll
            for (int t = 0; t < 16; t++)
                #pragma unroll
                for (int r = 0; r < 4; r++){ S[t][r] = __expf(S[t][r]-mx); sum += S[t][r]; }
            sum += __shfl_xor(sum, 16);
            sum += __shfl_xor(sum, 32);
            float rr = 1.f/sum;
            #pragma unroll
            for (int t = 0; t < 16; t++)
                #pragma unroll
                for (int r = 0; r < 4; r++) S[t][r] *= rr;
        }
        __syncthreads();   // all QK LDS reads done; safe to overwrite for PV

        #pragma unroll
        for (int hm = 0; hm < 2; hm++){
            #pragma unroll
            for (int mtl = 0; mtl < 8; mtl++){
                short4v p4;
                #pragma unroll
                for (int r = 0; r < 4; r++) p4[r] = (short)bf16_rn(S[hm*8+mtl][r]);
                int idx = (mtl>>1)*2560 + (wv*16 + l16)*40 + 16*(mtl&1) + quad*4;
                *(short4v*)&sP[idx] = p4;
            }
            {   // stage V half
                const int mp = tid & 63, c0 = tid >> 6;
                #pragma unroll
                for (int p = 0; p < 16; p++){
                    int c = c0 + 4*p;
                    float2 vv = *(const float2*)&J.V[bK + (size_t)(c*8+h)*256 + hm*128 + 2*mp];
                    unsigned short h0 = bf16_rn(vv.x), h1 = bf16_rn(vv.y);
                    unsigned short g0 = bf16_rn(vv.x - bf16_to_f(h0));
                    unsigned short g1 = bf16_rn(vv.y - bf16_to_f(h1));
                    int idx = (mp>>4)*2560 + c*40 + ((2*mp)&31);
                    *(unsigned*)&sVh[idx] = (unsigned)h0 | ((unsigned)h1 << 16);
                    *(unsigned*)&sVl[idx] = (unsigned)g0 | ((unsigned)g1 << 16);
                }
            }
            __syncthreads();
            #pragma unroll
            for (int ks = 0; ks < 4; ks++){
                int pidx = ks*2560 + (wv*16 + l16)*40 + quad*8;
                short8 bp = *(const short8*)&sP[pidx];
                #pragma unroll
                for (int ct = 0; ct < 4; ct++){
                    int vidx = ks*2560 + (ct*16 + l16)*40 + quad*8;
                    short8 vh = *(const short8*)&sVh[vidx];
                    short8 vl = *(const short8*)&sVl[vidx];
                    oac[ct] = __builtin_amdgcn_mfma_f32_16x16x32_bf16(vh, bp, oac[ct], 0, 0, 0);
                    oac[ct] = __builtin_amdgcn_mfma_f32_16x16x32_bf16(vl, bp, oac[ct], 0, 0, 0);
                }
            }
            __syncthreads();
        }
    }

    // ---- write this dg-group's partial O once (plain stores, no atomics) ----
    float* Od = dg ? J.O1 : J.O0;
    const int q = n0 + wv*16 + l16;
    #pragma unroll
    for (int ct = 0; ct < 4; ct++){
        #pragma unroll
        for (int r = 0; r < 4; r++){
            int c = ct*16 + quad*4 + r;
            Od[bQ + (size_t)(c*8+h)*256 + q] = oac[ct][r];
        }
    }
}

// ---------- LN over channels (strided), keeps [b][c][n] layout ----------
__global__ __launch_bounds__(64) void k_ln_pix(LnJobs jo,
    const float* __restrict__ g, const float* __restrict__ be)
{
    const int br = blockIdx.y;
    const int bn = blockIdx.x;
    const int b = bn >> 8, n = bn & 255;
    const int lane = threadIdx.x;
    const float* p = jo.in[br] + (size_t)b*IMG + n;
    float v[8]; float s = 0.f;
    #pragma unroll
    for (int i = 0; i < 8; i++){ v[i] = p[(size_t)(lane + 64*i)*256]; s += v[i]; }
    s = wave_sum(s);
    float mean = s * (1.f/512.f);
    float q = 0.f;
    #pragma unroll
    for (int i = 0; i < 8; i++){ float d = v[i]-mean; q += d*d; }
    q = wave_sum(q);
    float rstd = rsqrtf(q*(1.f/512.f) + 1e-5f);
    #pragma unroll
    for (int i = 0; i < 8; i++){
        int c = lane + 64*i;
        jo.out[br][(size_t)b*IMG + (size_t)c*256 + n] = (v[i]-mean)*rstd*g[c] + be[c];
    }
}

// ---------- host orchestration ----------
extern "C" void kernel_launch(void* const* d_in, const int* in_sizes, int n_in,
                              void* d_out, int out_size, void* d_ws, size_t ws_size,
                              hipStream_t stream)
{
    const float* xs    = (const float*)d_in[0];
    const float* xq    = (const float*)d_in[1];
    const float* qkvw  = (const float*)d_in[2];  const float* qkvb = (const float*)d_in[3];
    const float* paw   = (const float*)d_in[4];  const float* pab  = (const float*)d_in[5];
    const float* ln1g  = (const float*)d_in[6];  const float* ln1b = (const float*)d_in[7];
    const float* f1w   = (const float*)d_in[8];  const float* f1b  = (const float*)d_in[9];
    const float* f2w   = (const float*)d_in[10]; const float* f2b  = (const float*)d_in[11];
    const float* ln2g  = (const float*)d_in[12]; const float* ln2b = (const float*)d_in[13];
    const float* c1w   = (const float*)d_in[14]; const float* c1b  = (const float*)d_in[15];
    const float* c2w   = (const float*)d_in[16]; const float* c2b  = (const float*)d_in[17];
    const float* bng   = (const float*)d_in[18]; const float* bnb  = (const float*)d_in[19];
    const float* caqw  = (const float*)d_in[20]; const float* caqb = (const float*)d_in[21];
    const float* cakw  = (const float*)d_in[22]; const float* cakb = (const float*)d_in[23];
    const float* cavw  = (const float*)d_in[24]; const float* cavb = (const float*)d_in[25];
    const float* capw  = (const float*)d_in[26]; const float* capb = (const float*)d_in[27];
    const float* pqw   = (const float*)d_in[28]; const float* pqb  = (const float*)d_in[29];
    const float* pkw   = (const float*)d_in[30]; const float* pkb  = (const float*)d_in[31];
    const float* pvw   = (const float*)d_in[32]; const float* pvb  = (const float*)d_in[33];
    const float* ppw   = (const float*)d_in[34]; const float* ppb  = (const float*)d_in[35];
    const float* plng  = (const float*)d_in[36]; const float* plnb = (const float*)d_in[37];
    const float* plinw = (const float*)d_in[38]; const float* plinb= (const float*)d_in[39];

    const size_t SMF = 262144;  // small-scratch floats (2 branch regions of 131072)
    float* ws = (float*)d_ws;
    float* smb = ws;
    float* B[12];
    for (int i = 0; i < 12; i++) B[i] = ws + SMF + (size_t)i*BIGF;
    float* sa_s = B[0]; float* sa_q = B[1];
    float* ca_s = B[2]; float* ca_q = B[3];
    const bool paired_pixel = ws_size >= (SMF + 12*(size_t)BIGF)*sizeof(float) + 1024;

    auto SM = [&](int br){ return smb + (size_t)br*131072; };
    auto GAP=[&](int br){ return SM(br); };            auto QKV=[&](int br){ return SM(br)+4096; };
    auto OM =[&](int br){ return SM(br)+20480; };      auto AA =[&](int br){ return SM(br)+24576; };
    auto HB =[&](int br){ return SM(br)+28672; };      auto A2 =[&](int br){ return SM(br)+32768; };
    auto LNB=[&](int br){ return SM(br)+36864; };      auto S8 =[&](int br){ return SM(br)+40960; };
    auto ATW=[&](int br){ return SM(br)+106496; };     auto Q8 =[&](int br){ return SM(br)+107008; };
    auto K8 =[&](int br){ return SM(br)+111104; };

    const float bninv = 1.0f / sqrtf(1.0f + 1e-5f);
    float* out0 = (float*)d_out;
    float* out1 = out0 + (size_t)BIGF;

    // ================= ASRI (both branches paired) =================
    {
        GapJobs gj = {{xs, xq}, {GAP(0), GAP(1)}};
        k_gap<<<dim3(4096,2), 64, 0, stream>>>(gj);
        G8Jobs qj = {{{GAP(0), qkvw, qkvb, nullptr, QKV(0)}, {GAP(1), qkvw, qkvb, nullptr, QKV(1)}}};
        k_gemm8<<<dim3(2048,2), 64, 0, stream>>>(qj, 0, 0, 2048, 0);
        AAJobs aj = {{QKV(0), QKV(1)}, {OM(0), OM(1)}};
        k_asri_attn<<<dim3(64,2), 64, 0, stream>>>(aj);
        G8Jobs pj = {{{OM(0), paw, pab, QKV(0), AA(0)}, {OM(1), paw, pab, QKV(1), AA(1)}}};
        k_gemm8<<<dim3(512,2), 64, 0, stream>>>(pj, 1536, 2048, 512, 0);
        LnJobs l1 = {{AA(0), AA(1)}, {LNB(0), LNB(1)}};
        k_ln8<<<dim3(8,2), 64, 0, stream>>>(l1, ln1g, ln1b);
        G8Jobs fj = {{{LNB(0), f1w, f1b, nullptr, HB(0)}, {LNB(1), f1w, f1b, nullptr, HB(1)}}};
        k_gemm8<<<dim3(512,2), 64, 0, stream>>>(fj, 0, 0, 512, 1);
        G8Jobs f2j = {{{HB(0), f2w, f2b, AA(0), A2(0)}, {HB(1), f2w, f2b, AA(1), A2(1)}}};
        k_gemm8<<<dim3(512,2), 64, 0, stream>>>(f2j, 0, 512, 512, 0);
        LnJobs l2 = {{A2(0), A2(1)}, {LNB(0), LNB(1)}};
        k_ln8<<<dim3(8,2), 64, 0, stream>>>(l2, ln2g, ln2b);
        G8Jobs cj = {{{LNB(0), c1w, c1b, nullptr, S8(0)}, {LNB(1), c1w, c1b, nullptr, S8(1)}}};
        k_gemm8<<<dim3(8192,2), 64, 0, stream>>>(cj, 0, 0, 8192, 0);
        UpJobs uj = {{S8(0), S8(1)}, {B[4], B[5]}};
        k_up<<<dim3(4096,2), 256, 0, stream>>>(uj);
        ConvJobs c2j = {};
        c2j.j[0] = {B[4], nullptr, c2w, c2b, xs, bng, bnb, sa_s, CF_BN|CF_RELU|CF_RES};
        c2j.j[1] = {B[5], nullptr, c2w, c2b, xq, bng, bnb, sa_q, CF_BN|CF_RELU|CF_RES};
        k_convm<<<dim3(4,8,16), 512, 0, stream>>>(c2j, bninv);
    }

    // ================= SSCM (both branches paired) =================
    {
        GapJobs gj = {{sa_s, sa_q}, {GAP(0), GAP(1)}};
        k_gap<<<dim3(4096,2), 64, 0, stream>>>(gj);
        G8Jobs qj = {{{GAP(0), caqw, caqb, nullptr, Q8(0)},
                      {GAP(1), cakw, cakb, nullptr, K8(0)},
                      {GAP(1), caqw, caqb, nullptr, Q8(1)},
                      {GAP(0), cakw, cakb, nullptr, K8(1)}}};
        k_gemm8<<<dim3(512,4), 64, 0, stream>>>(qj, 0, 0, 512, 0);
        SAJobs sj = {{Q8(0), Q8(1)}, {K8(0), K8(1)}, {ATW(0), ATW(1)}};
        k_sscm_attn<<<dim3(64,2), 64, 0, stream>>>(sj);
        ConvJobs vj = {};
        vj.j[0] = {sa_q, nullptr, cavw, cavb, nullptr, nullptr, nullptr, B[4], 0};
        vj.j[1] = {sa_s, nullptr, cavw, cavb, nullptr, nullptr, nullptr, B[5], 0};
        k_convm<<<dim3(4,8,16), 512, 0, stream>>>(vj, 1.f);
        SPJobs pj = {{ATW(0), ATW(1)}, {B[4], B[5]}, {B[6], B[7]}};
        k_sscm_apply<<<dim3(4096,2), 256, 0, stream>>>(pj);
        ConvJobs aj = {};
        aj.j[0] = {B[6], nullptr, capw, capb, nullptr, nullptr, nullptr, ca_s, CF_RELU};
        aj.j[1] = {B[7], nullptr, capw, capb, nullptr, nullptr, nullptr, ca_q, CF_RELU};
        k_convm<<<dim3(4,8,16), 512, 0, stream>>>(aj, 1.f);
    }

    // ================= PIXEL =================
    if (paired_pixel){
        ConvJobs qkvj = {};
        qkvj.j[0] = {sa_s, nullptr, pqw, pqb, nullptr, nullptr, nullptr, B[4],  0};
        qkvj.j[1] = {ca_q, nullptr, pkw, pkb, nullptr, nullptr, nullptr, B[5],  0};
        qkvj.j[2] = {ca_q, nullptr, pvw, pvb, nullptr, nullptr, nullptr, B[6],  0};
        qkvj.j[3] = {sa_q, nullptr, pqw, pqb, nullptr, nullptr, nullptr, B[8],  0};
        qkvj.j[4] = {ca_s, nullptr, pkw, pkb, nullptr, nullptr, nullptr, B[9],  0};
        qkvj.j[5] = {ca_s, nullptr, pvw, pvb, nullptr, nullptr, nullptr, B[10], 0};
        k_convm<<<dim3(4,8,48), 512, 0, stream>>>(qkvj, 1.f);
        // partials: dg0 -> B[7]/B[11], dg1 -> out0/out1 (d_out free until pp)
        PixJobs pxj = {{{B[4], B[5], B[6], B[7],  out0},
                        {B[8], B[9], B[10], B[11], out1}}};
        k_pixel_mfma<<<dim3(8,16,8), 256, 0, stream>>>(pxj);
        ConvJobs ppj = {};
        ppj.j[0] = {B[7],  out0, ppw, ppb, sa_s, nullptr, nullptr, B[5], CF_RES};
        ppj.j[1] = {B[11], out1, ppw, ppb, sa_q, nullptr, nullptr, B[9], CF_RES};
        k_convm<<<dim3(4,8,16), 512, 0, stream>>>(ppj, 1.f);
        LnJobs lj = {{B[5], B[9]}, {B[4], B[8]}};
        k_ln_pix<<<dim3(2048,2), 64, 0, stream>>>(lj, plng, plnb);
        ConvJobs lnj = {};
        lnj.j[0] = {B[4], nullptr, plinw, plinb, nullptr, nullptr, nullptr, out0, CF_RELU};
        lnj.j[1] = {B[8], nullptr, plinw, plinb, nullptr, nullptr, nullptr, out1, CF_RELU};
        k_convm<<<dim3(4,8,16), 512, 0, stream>>>(lnj, 1.f);
    } else {
        auto pixel1 = [&](const float* x1, const float* x2, float* out){
            ConvJobs qkvj = {};
            qkvj.j[0] = {x1, nullptr, pqw, pqb, nullptr, nullptr, nullptr, B[4], 0};
            qkvj.j[1] = {x2, nullptr, pkw, pkb, nullptr, nullptr, nullptr, B[5], 0};
            qkvj.j[2] = {x2, nullptr, pvw, pvb, nullptr, nullptr, nullptr, B[6], 0};
            k_convm<<<dim3(4,8,24), 512, 0, stream>>>(qkvj, 1.f);
            PixJobs pxj = {{{B[4], B[5], B[6], B[7], out},
                            {B[4], B[5], B[6], B[7], out}}};
            k_pixel_mfma<<<dim3(8,8,8), 256, 0, stream>>>(pxj);
            ConvJobs ppj = {};
            ppj.j[0] = {B[7], out, ppw, ppb, x1, nullptr, nullptr, B[5], CF_RES};
            k_convm<<<dim3(4,8,8), 512, 0, stream>>>(ppj, 1.f);
            LnJobs lj = {{B[5], B[5]}, {B[4], B[4]}};
            k_ln_pix<<<dim3(2048,1), 64, 0, stream>>>(lj, plng, plnb);
            ConvJobs lnj = {};
            lnj.j[0] = {B[4], nullptr, plinw, plinb, nullptr, nullptr, nullptr, out, CF_RELU};
            k_convm<<<dim3(4,8,8), 512, 0, stream>>>(lnj, 1.f);
        };
        pixel1(sa_s, ca_q, out0);
        pixel1(sa_q, ca_s, out1);
    }

    (void)in_sizes; (void)n_in; (void)out_size;
}